// Round 14
// baseline (358.905 us; speedup 1.0000x reference)
//
#include <hip/hip_runtime.h>
#include <cstdint>
#include <cstddef>

#define B 64
#define PCH 512
#define O_CAPS 32
#define OD 16
#define IDC 8
#define I_CAPS 4096
#define ICHUNK 16
#define NPBLK 256  // I_CAPS / ICHUNK
#define KDIM 4608  // 512*9
#define KSPLIT 128 // caps_v0 k-splits (k-range 256 each)

typedef __attribute__((ext_vector_type(8))) short bf16x8;
typedef __attribute__((ext_vector_type(4))) float f32x4;
typedef __attribute__((ext_vector_type(8))) unsigned short u16x8;
typedef _Float16 h2 __attribute__((ext_vector_type(2)));
typedef _Float16 f16x8v __attribute__((ext_vector_type(8)));

#if defined(__has_builtin)
#if __has_builtin(__builtin_amdgcn_fdot2)
#define HAVE_FDOT2 1
#endif
#endif

// workspace layout (in floats)
#define OFF_PH 0                    // pose f16: 2,097,152 ushorts
#define SZ_PH (B * I_CAPS * IDC / 2)                  // 1,048,576 floats
#define OFF_PART (OFF_PH + SZ_PH)
#define SZ_PART ((size_t)NPBLK * 4 * 16 * 512)        // 8,388,608
// aim (bf16, 9,437,184 float-equiv) occupies part + 1M spill; dead before
// caps_v0/pv0/part are written. pv0 now 128*64*512 = 4,194,304 floats (fits).
#define OFF_AIM OFF_PART
#define OFF_PV0 OFF_PART            // 4,194,304 floats, after aim dead
#define OFF_SPILL (OFF_PART + SZ_PART)                // aim tail
#define OFF_VBUF (OFF_SPILL + 1048576)
#define SZ_V (B * O_CAPS * OD)                        // 32,768
#define OFF_VBUF2 (OFF_VBUF + SZ_V)
#define OFF_OUTC (OFF_VBUF2 + SZ_V)
#define OFF_WB (OFF_OUTC + SZ_V)                      // bf16 512*4608
#define OFF_BIAS (OFF_WB + (PCH * KDIM) / 2)
#define OFF_WRH (OFF_BIAS + 512)                      // f16 caps_w
#define SZ_WRH ((size_t)O_CAPS * I_CAPS * OD * IDC / 2)  // 8,388,608 floats

__device__ inline unsigned short f2bf(float f) {
  union { float f; unsigned int u; } v; v.f = f;
  unsigned int r = v.u + 0x7fff + ((v.u >> 16) & 1);  // RNE
  return (unsigned short)(r >> 16);
}

union HU { u16x8 v; _Float16 h[8]; h2 p[4]; };

__device__ inline unsigned short f2h(float f) {
  union { _Float16 h; unsigned short u; } c;
  c.h = (_Float16)f;  // v_cvt_f16_f32, RNE
  return c.u;
}

// ---------------------------------------------------------------------------
// cast_f16x8: fp32 -> f16 flat copy, 8 elems/thread (caps_w -> wrh).
// ---------------------------------------------------------------------------
__global__ __launch_bounds__(256) void cast_f16x8(
    const float* __restrict__ src, unsigned short* __restrict__ dst) {
  const size_t t = (size_t)blockIdx.x * 256 + threadIdx.x;
  const float4* s = (const float4*)src + t * 2;
  const float4 a = s[0], b = s[1];
  HU u;
  u.h[0] = (_Float16)a.x; u.h[1] = (_Float16)a.y;
  u.h[2] = (_Float16)a.z; u.h[3] = (_Float16)a.w;
  u.h[4] = (_Float16)b.x; u.h[5] = (_Float16)b.y;
  u.h[6] = (_Float16)b.z; u.h[7] = (_Float16)b.w;
  ((u16x8*)dst)[t] = u.v;
}

// ---------------------------------------------------------------------------
// prep_wb: Wb[n][k] = bf16(conv_w[n][k] * inv[n]); bias[n] = beta - mean*inv.
// ---------------------------------------------------------------------------
__global__ __launch_bounds__(256) void prep_wb(
    const float* __restrict__ cw, const float* __restrict__ gamma,
    const float* __restrict__ beta, const float* __restrict__ mean,
    const float* __restrict__ var, unsigned short* __restrict__ wb,
    float* __restrict__ bias) {
  const int n = blockIdx.x;
  const float inv = gamma[n] * rsqrtf(var[n] + 1e-5f);
  if (threadIdx.x == 0) bias[n] = beta[n] - mean[n] * inv;
  for (int k = threadIdx.x; k < KDIM; k += 256)
    wb[(size_t)n * KDIM + k] = f2bf(cw[(size_t)n * KDIM + k] * inv);
}

// ---------------------------------------------------------------------------
// prep_aim: im2col to bf16. Aim[m=(b,px)][k=ci*9+tap]
// ---------------------------------------------------------------------------
__global__ __launch_bounds__(256) void prep_aim(
    const float* __restrict__ x, unsigned short* __restrict__ aim) {
  __shared__ float lxp[32 * 100];
  const int b = blockIdx.x;
  const int ci0 = blockIdx.y * 32;
  const int tid = threadIdx.x;
  for (int t = tid; t < 3200; t += 256) lxp[t] = 0.f;
  __syncthreads();
  for (int t = tid; t < 2048; t += 256) {
    const int ci = t >> 6, px = t & 63;
    lxp[ci * 100 + 11 + (px >> 3) * 10 + (px & 7)] =
        x[((size_t)b * PCH + ci0 + ci) * 64 + px];
  }
  __syncthreads();
  for (int t = tid; t < 4608; t += 256) {
    const int px = t / 72;
    const int kk = (t - px * 72) * 4;
    unsigned short v[4];
#pragma unroll
    for (int j = 0; j < 4; ++j) {
      const int k = kk + j;
      const int ci = k / 9;
      const int tap = k - ci * 9;
      const int kh = tap / 3, kw = tap - kh * 3;
      v[j] = f2bf(lxp[ci * 100 + ((px >> 3) + kh) * 10 + (px & 7) + kw]);
    }
    ushort4* dst =
        (ushort4*)(aim + (size_t)(b * 64 + px) * KDIM + ci0 * 9 + kk);
    *dst = make_ushort4(v[0], v[1], v[2], v[3]);
  }
}

// ---------------------------------------------------------------------------
// conv_gemm: 64x64 tiles, mfma 16x16x32_bf16, global_load_lds staging with
// XOR swizzle, fused bias+ReLU+squash -> pose_h (f16).
// ---------------------------------------------------------------------------
__global__ __launch_bounds__(256) void conv_gemm(
    const unsigned short* __restrict__ aim, const unsigned short* __restrict__ wb,
    const float* __restrict__ bias, unsigned short* __restrict__ pose_h) {
  __shared__ unsigned short lA[64 * 64];
  __shared__ unsigned short lB[64 * 64];
  const int tid = threadIdx.x;
  const int lane = tid & 63, wv = tid >> 6;
  const int wm = wv & 1, wn = wv >> 1;
  const int m0 = blockIdx.x * 64;  // = batch * 64
  const int n0 = blockIdx.y * 64;
  const int rsub = lane >> 3, seg = lane & 7;

  f32x4 acc[2][2];
#pragma unroll
  for (int a = 0; a < 2; ++a)
#pragma unroll
    for (int c = 0; c < 2; ++c) acc[a][c] = (f32x4){0.f, 0.f, 0.f, 0.f};

  for (int k0 = 0; k0 < KDIM; k0 += 64) {
    __syncthreads();
#pragma unroll
    for (int it = 0; it < 2; ++it) {
      const int r = it * 32 + wv * 8 + rsub;
      const int c = seg ^ (r & 7);
      const unsigned short* ga = aim + (size_t)(m0 + r) * KDIM + k0 + c * 8;
      __builtin_amdgcn_global_load_lds(
          (const __attribute__((address_space(1))) void*)ga,
          (__attribute__((address_space(3))) void*)(lA + (it * 32 + wv * 8) * 64),
          16, 0, 0);
      const unsigned short* gb = wb + (size_t)(n0 + r) * KDIM + k0 + c * 8;
      __builtin_amdgcn_global_load_lds(
          (const __attribute__((address_space(1))) void*)gb,
          (__attribute__((address_space(3))) void*)(lB + (it * 32 + wv * 8) * 64),
          16, 0, 0);
    }
    __syncthreads();
#pragma unroll
    for (int kc = 0; kc < 2; ++kc) {
      const int g = kc * 4 + (lane >> 4);
      const int ml = wm * 32 + (lane & 15);
      const int nl = wn * 32 + (lane & 15);
      const int sa = (g ^ (ml & 7)) * 8;
      const int sb = (g ^ (nl & 7)) * 8;
      const bf16x8 a0 = *(const bf16x8*)(lA + (ml + 0) * 64 + sa);
      const bf16x8 a1 = *(const bf16x8*)(lA + (ml + 16) * 64 + sa);
      const bf16x8 b0 = *(const bf16x8*)(lB + (nl + 0) * 64 + sb);
      const bf16x8 b1 = *(const bf16x8*)(lB + (nl + 16) * 64 + sb);
      acc[0][0] = __builtin_amdgcn_mfma_f32_16x16x32_bf16(a0, b0, acc[0][0], 0, 0, 0);
      acc[0][1] = __builtin_amdgcn_mfma_f32_16x16x32_bf16(a0, b1, acc[0][1], 0, 0, 0);
      acc[1][0] = __builtin_amdgcn_mfma_f32_16x16x32_bf16(a1, b0, acc[1][0], 0, 0, 0);
      acc[1][1] = __builtin_amdgcn_mfma_f32_16x16x32_bf16(a1, b1, acc[1][1], 0, 0, 0);
    }
  }

  const int bq = blockIdx.x;
  float bsv[2];
#pragma unroll
  for (int ni = 0; ni < 2; ++ni)
    bsv[ni] = bias[n0 + wn * 32 + ni * 16 + (lane & 15)];
#pragma unroll
  for (int mi = 0; mi < 2; ++mi) {
#pragma unroll
    for (int ni = 0; ni < 2; ++ni) {
      const int n = n0 + wn * 32 + ni * 16 + (lane & 15);
#pragma unroll
      for (int reg = 0; reg < 4; ++reg) {
        float v = fmaxf(acc[mi][ni][reg] + bsv[ni], 0.f);
        float s2 = v * v;
        s2 += __shfl_xor(s2, 1, 64);
        s2 += __shfl_xor(s2, 2, 64);
        s2 += __shfl_xor(s2, 4, 64);
        const float sc = s2 / (1.f + s2) / (sqrtf(s2) + 1e-8f);
        const int px = wm * 32 + mi * 16 + (lane >> 4) * 4 + reg;
        pose_h[((size_t)bq * I_CAPS + (n >> 3) * 64 + px) * IDC + (n & 7)] =
            f2h(v * sc);
      }
    }
  }
}

// ---------------------------------------------------------------------------
// caps_v0 v2: phase-0 routing as f16 MFMA GEMM (c uniform; 1/32 in reduce).
// R13 analysis: grid (8,32)=256 blocks = 4 waves/CU (12.5% occ) ->
// latency-bound. v2: 4x finer k-split, grid (8, KSPLIT=128) = 1024 blocks
// = 16 waves/CU. Each ks covers 256 k (4 kt x 64). Traffic unchanged
// (same wrh/pose re-read); pv0 = 128*64*512 = 4.2M floats (fits part).
// ---------------------------------------------------------------------------
__global__ __launch_bounds__(256) void caps_v0(
    const unsigned short* __restrict__ pose_h,
    const unsigned short* __restrict__ wrh, float* __restrict__ pv0) {
  __shared__ unsigned short lA[64 * 64];
  __shared__ unsigned short lB[64 * 64];
  const int tid = threadIdx.x;
  const int lane = tid & 63, wv = tid >> 6;
  const int wm = wv & 1, wn = wv >> 1;
  const int o0 = blockIdx.x * 4;
  const int ks = blockIdx.y;
  const int rsub = lane >> 3, seg = lane & 7;

  f32x4 acc[2][2];
#pragma unroll
  for (int a = 0; a < 2; ++a)
#pragma unroll
    for (int c = 0; c < 2; ++c) acc[a][c] = (f32x4){0.f, 0.f, 0.f, 0.f};

  for (int kt = 0; kt < 4; ++kt) {
    const int k0 = ks * 256 + kt * 64;
    const int i0 = k0 >> 3;
    __syncthreads();
#pragma unroll
    for (int it = 0; it < 2; ++it) {
      const int r = it * 32 + wv * 8 + rsub;
      const int c = seg ^ (r & 7);
      const unsigned short* ga = pose_h + (size_t)r * 32768 + k0 + c * 8;
      __builtin_amdgcn_global_load_lds(
          (const __attribute__((address_space(1))) void*)ga,
          (__attribute__((address_space(3))) void*)(lA + (it * 32 + wv * 8) * 64),
          16, 0, 0);
    }
#pragma unroll
    for (int h = 0; h < 2; ++h) {
      const int idx = h * 256 + tid;
      const int d = idx & 15;
      const int il = (idx >> 4) & 7;
      const int ol = idx >> 7;
      const u16x8 v = *(const u16x8*)(wrh + (size_t)(o0 + ol) * 524288 +
                                      (size_t)(i0 + il) * 128 + d * 8);
      const int np = ol * 16 + d;
      *(u16x8*)(lB + np * 64 + (il ^ (np & 7)) * 8) = v;
    }
    __syncthreads();
#pragma unroll
    for (int kc = 0; kc < 2; ++kc) {
      const int g = kc * 4 + (lane >> 4);
      const int ml = wm * 32 + (lane & 15);
      const int nl = wn * 32 + (lane & 15);
      const int sa = (g ^ (ml & 7)) * 8;
      const int sb = (g ^ (nl & 7)) * 8;
      const f16x8v a0 = *(const f16x8v*)(lA + (ml + 0) * 64 + sa);
      const f16x8v a1 = *(const f16x8v*)(lA + (ml + 16) * 64 + sa);
      const f16x8v b0 = *(const f16x8v*)(lB + (nl + 0) * 64 + sb);
      const f16x8v b1 = *(const f16x8v*)(lB + (nl + 16) * 64 + sb);
      acc[0][0] = __builtin_amdgcn_mfma_f32_16x16x32_f16(a0, b0, acc[0][0], 0, 0, 0);
      acc[0][1] = __builtin_amdgcn_mfma_f32_16x16x32_f16(a0, b1, acc[0][1], 0, 0, 0);
      acc[1][0] = __builtin_amdgcn_mfma_f32_16x16x32_f16(a1, b0, acc[1][0], 0, 0, 0);
      acc[1][1] = __builtin_amdgcn_mfma_f32_16x16x32_f16(a1, b1, acc[1][1], 0, 0, 0);
    }
  }
#pragma unroll
  for (int mi = 0; mi < 2; ++mi) {
#pragma unroll
    for (int ni = 0; ni < 2; ++ni) {
      const int n = blockIdx.x * 64 + wn * 32 + ni * 16 + (lane & 15);
#pragma unroll
      for (int reg = 0; reg < 4; ++reg) {
        const int m = wm * 32 + mi * 16 + (lane >> 4) * 4 + reg;
        pv0[(size_t)(ks * 64 + m) * 512 + n] = acc[mi][ni][reg];
      }
    }
  }
}

// ---------------------------------------------------------------------------
// reduce_v0: sum KSPLIT k-splits, scale 1/32, squash over d -> vbuf (= v0).
// ---------------------------------------------------------------------------
__global__ __launch_bounds__(256) void reduce_v0(
    const float* __restrict__ pv0, float* __restrict__ vbuf) {
  const int t = blockIdx.x * 256 + threadIdx.x;
  const int b = t >> 9;
  const int r = t & 511;
  float s = 0.f;
#pragma unroll 8
  for (int ks = 0; ks < KSPLIT; ++ks)
    s += pv0[(size_t)(ks * 64 + b) * 512 + r];
  s *= (1.0f / 32.0f);
  float sq = s * s;
  sq += __shfl_xor(sq, 1, 64);
  sq += __shfl_xor(sq, 2, 64);
  sq += __shfl_xor(sq, 4, 64);
  sq += __shfl_xor(sq, 8, 64);
  const float sc = sq / (1.f + sq) / (sqrtf(sq) + 1e-8f);
  vbuf[t] = s * sc;
}

// ---------------------------------------------------------------------------
// Routing phase v10: v9 (59.3 us, VALU 59%) + pose tile prefetch. The
// per-(ii,bb) pk load was a wave-uniform 16B GLOBAL load (~200cy L2) at the
// head of the fdot2 chain, 32x per wave. Stage the block's 16i x 16b pose
// tile (4KB) into LDS in the prologue (coalesced; covered by the existing
// barrier); pk becomes a broadcast ds_read_b128. LDS 16.9 -> 21 KB (still
// >= 4 blocks/CU).
// ---------------------------------------------------------------------------
__global__ __launch_bounds__(512, 4) void routing_phase(
    const unsigned short* __restrict__ pose_h,
    const unsigned short* __restrict__ wrh,
    const float* __restrict__ vb, float* __restrict__ partials) {
  __shared__ u16x8 lw[2][8 * 65];   // 2 x 8.3 KB
  __shared__ u16x8 ppose[16][16];   // [i][b] 4 KB
  const int tid = threadIdx.x;
  const int lane = tid & 63;
  const int wv = tid >> 6;  // 0..7
  const int o = lane >> 1, dh = lane & 1;
  const int i0 = blockIdx.x * ICHUNK;
  const int b0 = blockIdx.y * 16;

  const int sl = tid >> 3;  // 0..63
  const int sq = tid & 7;
  const u16x8* wr8 = (const u16x8*)wrh;

  float acc[2][8];
  float vr[2][8];
#pragma unroll
  for (int bb = 0; bb < 2; ++bb) {
    const int b = b0 + wv * 2 + bb;
    const float4* vp =
        (const float4*)(vb + ((size_t)(b * O_CAPS + o) * OD) + dh * 8);
    const float4 v0 = vp[0], v1 = vp[1];
    vr[bb][0] = v0.x; vr[bb][1] = v0.y; vr[bb][2] = v0.z; vr[bb][3] = v0.w;
    vr[bb][4] = v1.x; vr[bb][5] = v1.y; vr[bb][6] = v1.z; vr[bb][7] = v1.w;
#pragma unroll
    for (int j = 0; j < 8; ++j) acc[bb][j] = 0.f;
  }

  auto stage = [&](int i, int buf) {
    lw[buf][sq * 65 + sl] =
        wr8[(size_t)(sl >> 1) * (I_CAPS * 16) + (size_t)i * 16 +
            (sl & 1) * 8 + sq];
  };

  if (tid < 256) {  // pose tile: [i][b], coalesced (16 lanes x 16B per b)
    const int pb = tid >> 4, pi = tid & 15;
    ppose[pi][pb] =
        *(const u16x8*)(pose_h + ((size_t)(b0 + pb) * I_CAPS + i0 + pi) * IDC);
  }
  stage(i0, 0);
  __syncthreads();

  for (int ii = 0; ii < ICHUNK; ++ii) {
    const int buf = ii & 1;
    if (ii + 1 < ICHUNK) stage(i0 + ii + 1, buf ^ 1);
    HU w[8];
#pragma unroll
    for (int q = 0; q < 8; ++q) w[q].v = lw[buf][q * 65 + lane];
#pragma unroll
    for (int bb = 0; bb < 2; ++bb) {
      HU pk;
      pk.v = ppose[ii][wv * 2 + bb];  // LDS broadcast, conflict-free
      float X[8];
#pragma unroll
      for (int j = 0; j < 8; ++j) {
#ifdef HAVE_FDOT2
        float s = __builtin_amdgcn_fdot2(w[j].p[3], pk.p[3], 0.f, false);
        s = __builtin_amdgcn_fdot2(w[j].p[2], pk.p[2], s, false);
        s = __builtin_amdgcn_fdot2(w[j].p[1], pk.p[1], s, false);
        X[j] = __builtin_amdgcn_fdot2(w[j].p[0], pk.p[0], s, false);
#else
        float s = 0.f;
#pragma unroll
        for (int k = 0; k < 8; ++k) s += (float)w[j].h[k] * (float)pk.h[k];
        X[j] = s;
#endif
      }
      float lg = 0.f;
#pragma unroll
      for (int j = 0; j < 8; ++j) lg += vr[bb][j] * X[j];
      lg += __shfl_xor(lg, 1, 64);  // full v.X over 16 d
      const float e = __expf(lg);   // no max-subtract: |lg| small
      float sm = e;
#pragma unroll
      for (int s = 2; s < 64; s <<= 1) sm += __shfl_xor(sm, s, 64);
      const float c = e / sm;
#pragma unroll
      for (int j = 0; j < 8; ++j) acc[bb][j] += c * X[j];
    }
    __syncthreads();
  }

  const size_t pbase = ((size_t)blockIdx.x * 4 + blockIdx.y) * (16 * 512);
#pragma unroll
  for (int bb = 0; bb < 2; ++bb) {
    const int bl = wv * 2 + bb;
    float4* dst =
        (float4*)(partials + pbase + (size_t)bl * 512 + o * 16 + dh * 8);
    dst[0] = make_float4(acc[bb][0], acc[bb][1], acc[bb][2], acc[bb][3]);
    dst[1] = make_float4(acc[bb][4], acc[bb][5], acc[bb][6], acc[bb][7]);
  }
}

// ---------------------------------------------------------------------------
// reduce_squash<ADDV>: sum 256 i-chunk partials, squash over d; if ADDV,
// add vprev (producing vsum = v0 + v1 for the final routing pass).
// Partials layout: [(iblk*4 + bgrp)][16 b][512] (R3-proven).
// ---------------------------------------------------------------------------
template <int ADDV>
__global__ __launch_bounds__(256) void reduce_squash(
    const float* __restrict__ partials, const float* __restrict__ vprev,
    float* __restrict__ dst) {
  const int t = blockIdx.x * 256 + threadIdx.x;  // (b, od)
  const int b = t >> 9;
  const int r = t & 511;
  const int bg = b >> 4, bl = b & 15;
  const size_t elem = (size_t)bl * 512 + r;
  float s = 0.f;
  for (int blk = 0; blk < NPBLK; ++blk)
    s += partials[(size_t)(blk * 4 + bg) * (16 * 512) + elem];
  float sq = s * s;
  sq += __shfl_xor(sq, 1, 64);
  sq += __shfl_xor(sq, 2, 64);
  sq += __shfl_xor(sq, 4, 64);
  sq += __shfl_xor(sq, 8, 64);
  const float sc = sq / (1.f + sq) / (sqrtf(sq) + 1e-8f);
  float val = s * sc;
  if (ADDV) val += vprev[t];
  dst[t] = val;
}

// ---------------------------------------------------------------------------
// vae_head: fused fc1(relu)+fc2(z_mu)+fc_var over 2048 rows; 512 blk x 1024.
// ---------------------------------------------------------------------------
__global__ __launch_bounds__(1024) void vae_head(
    const float* __restrict__ outc, const float* __restrict__ w1,
    const float* __restrict__ b1, const float* __restrict__ w2,
    const float* __restrict__ b2, const float* __restrict__ wv,
    const float* __restrict__ bv, float* __restrict__ dout) {
  __shared__ float lo[4][16];
  __shared__ float lh[4][1024];
  __shared__ float red[16][4][64];
  const int n0 = blockIdx.x * 4;
  const int tid = threadIdx.x;
  if (tid < 64) lo[tid >> 4][tid & 15] = outc[(size_t)n0 * 16 + tid];
  __syncthreads();

  {
    const float bb = b1[tid];
    float h0 = bb, h1 = bb, h2v = bb, h3 = bb;
#pragma unroll
    for (int k = 0; k < 16; ++k) {
      const float w = w1[(size_t)k * 1024 + tid];
      h0 += lo[0][k] * w;
      h1 += lo[1][k] * w;
      h2v += lo[2][k] * w;
      h3 += lo[3][k] * w;
    }
    lh[0][tid] = fmaxf(h0, 0.f);
    lh[1][tid] = fmaxf(h1, 0.f);
    lh[2][tid] = fmaxf(h2v, 0.f);
    lh[3][tid] = fmaxf(h3, 0.f);
  }
  __syncthreads();

  const int m = tid & 63, sl = tid >> 6;
  {
    float a0 = 0.f, a1 = 0.f, a2 = 0.f, a3 = 0.f;
    const int j0 = sl * 64;
#pragma unroll 4
    for (int jj = 0; jj < 64; ++jj) {
      const int j = j0 + jj;
      const float w = w2[(size_t)j * 64 + m];
      a0 += lh[0][j] * w;
      a1 += lh[1][j] * w;
      a2 += lh[2][j] * w;
      a3 += lh[3][j] * w;
    }
    red[sl][0][m] = a0;
    red[sl][1][m] = a1;
    red[sl][2][m] = a2;
    red[sl][3][m] = a3;
  }
  __syncthreads();

  if (tid < 256) {
    const int r = tid >> 6;
    float z = b2[m];
#pragma unroll
    for (int s = 0; s < 16; ++s) z += red[s][r][m];
    const int n = n0 + r;
    dout[n * 64 + m] = z;
    dout[131072 + n * 64 + m] = z;
    float sv = bv[m];
#pragma unroll
    for (int k = 0; k < 16; ++k) sv += lo[r][k] * wv[(size_t)k * 64 + m];
    const float sp =
        (sv > 0.f) ? (sv + log1pf(__expf(-sv))) : log1pf(__expf(sv));
    dout[262144 + n * 64 + m] = sp + 1e-8f;
  }
}

// ---------------------------------------------------------------------------
extern "C" void kernel_launch(void* const* d_in, const int* in_sizes, int n_in,
                              void* d_out, int out_size, void* d_ws,
                              size_t ws_size, hipStream_t stream) {
  const float* x = (const float*)d_in[0];
  const float* conv_w = (const float*)d_in[1];
  const float* bn_gamma = (const float*)d_in[2];
  const float* bn_beta = (const float*)d_in[3];
  const float* bn_mean = (const float*)d_in[4];
  const float* bn_var = (const float*)d_in[5];
  const float* caps_w = (const float*)d_in[6];
  const float* fcm_w1 = (const float*)d_in[7];
  const float* fcm_b1 = (const float*)d_in[8];
  const float* fcm_w2 = (const float*)d_in[9];
  const float* fcm_b2 = (const float*)d_in[10];
  const float* fcv_w = (const float*)d_in[11];
  const float* fcv_b = (const float*)d_in[12];
  float* out = (float*)d_out;
  float* ws = (float*)d_ws;

  unsigned short* pose_h = (unsigned short*)(ws + OFF_PH);
  float* part = ws + OFF_PART;
  float* pv0 = ws + OFF_PV0;
  float* vbuf = ws + OFF_VBUF;
  float* vbuf2 = ws + OFF_VBUF2;
  float* outc = ws + OFF_OUTC;
  unsigned short* wbq = (unsigned short*)(ws + OFF_WB);
  float* bias = ws + OFF_BIAS;
  unsigned short* wrh = (unsigned short*)(ws + OFF_WRH);
  unsigned short* aim = (unsigned short*)(ws + OFF_AIM);

  cast_f16x8<<<8192, 256, 0, stream>>>(caps_w, wrh);
  prep_wb<<<512, 256, 0, stream>>>(conv_w, bn_gamma, bn_beta, bn_mean, bn_var,
                                   wbq, bias);
  prep_aim<<<dim3(64, 16), 256, 0, stream>>>(x, aim);
  conv_gemm<<<dim3(64, 8), 256, 0, stream>>>(aim, wbq, bias, pose_h);

  // iter 0: uniform c as f16 MFMA GEMM -> v0 (128-way k-split)
  caps_v0<<<dim3(8, KSPLIT), 256, 0, stream>>>(pose_h, wrh, pv0);
  reduce_v0<<<128, 256, 0, stream>>>(pv0, vbuf);

  // iter 1: logits = v0.X
  routing_phase<<<dim3(NPBLK, 4), 512, 0, stream>>>(pose_h, wrh, vbuf, part);
  reduce_squash<1><<<128, 256, 0, stream>>>(part, vbuf, vbuf2);  // vsum = v0+v1

  // iter 2: logits = (v0+v1).X
  routing_phase<<<dim3(NPBLK, 4), 512, 0, stream>>>(pose_h, wrh, vbuf2, part);
  reduce_squash<0><<<128, 256, 0, stream>>>(part, nullptr, outc);

  vae_head<<<512, 1024, 0, stream>>>(outc, fcm_w1, fcm_b1, fcm_w2, fcm_b2,
                                     fcv_w, fcv_b, out);
}

// Round 15
// 350.603 us; speedup vs baseline: 1.0237x; 1.0237x over previous
//
#include <hip/hip_runtime.h>
#include <cstdint>
#include <cstddef>

#define B 64
#define PCH 512
#define O_CAPS 32
#define OD 16
#define IDC 8
#define I_CAPS 4096
#define ICHUNK 16
#define NPBLK 256  // I_CAPS / ICHUNK
#define KDIM 4608  // 512*9
#define KSPLIT 128 // caps_v0 k-splits (k-range 256 each)

typedef __attribute__((ext_vector_type(8))) short bf16x8;
typedef __attribute__((ext_vector_type(4))) float f32x4;
typedef __attribute__((ext_vector_type(8))) unsigned short u16x8;
typedef _Float16 h2 __attribute__((ext_vector_type(2)));
typedef _Float16 f16x8v __attribute__((ext_vector_type(8)));

#if defined(__has_builtin)
#if __has_builtin(__builtin_amdgcn_fdot2)
#define HAVE_FDOT2 1
#endif
#endif

// workspace layout (in floats)
#define OFF_PH 0                    // pose f16: 2,097,152 ushorts
#define SZ_PH (B * I_CAPS * IDC / 2)                  // 1,048,576 floats
#define OFF_PART (OFF_PH + SZ_PH)
#define SZ_PART ((size_t)NPBLK * 4 * 16 * 512)        // 8,388,608
// aim (bf16, 9,437,184 float-equiv) occupies part + 1M spill; dead before
// caps_v0/pv0/part are written. pv0 = 128*64*512 = 4,194,304 floats (fits).
#define OFF_AIM OFF_PART
#define OFF_PV0 OFF_PART            // 4,194,304 floats, after aim dead
#define OFF_SPILL (OFF_PART + SZ_PART)                // aim tail
#define OFF_VBUF (OFF_SPILL + 1048576)
#define SZ_V (B * O_CAPS * OD)                        // 32,768
#define OFF_VBUF2 (OFF_VBUF + SZ_V)
#define OFF_OUTC (OFF_VBUF2 + SZ_V)
#define OFF_WB (OFF_OUTC + SZ_V)                      // bf16 512*4608
#define OFF_BIAS (OFF_WB + (PCH * KDIM) / 2)
#define OFF_WRH (OFF_BIAS + 512)                      // f16 caps_w
#define SZ_WRH ((size_t)O_CAPS * I_CAPS * OD * IDC / 2)  // 8,388,608 floats

__device__ inline unsigned short f2bf(float f) {
  union { float f; unsigned int u; } v; v.f = f;
  unsigned int r = v.u + 0x7fff + ((v.u >> 16) & 1);  // RNE
  return (unsigned short)(r >> 16);
}

union HU { u16x8 v; _Float16 h[8]; h2 p[4]; };

__device__ inline unsigned short f2h(float f) {
  union { _Float16 h; unsigned short u; } c;
  c.h = (_Float16)f;  // v_cvt_f16_f32, RNE
  return c.u;
}

// ---------------------------------------------------------------------------
// cast_f16x8: fp32 -> f16 flat copy, 8 elems/thread (caps_w -> wrh).
// ---------------------------------------------------------------------------
__global__ __launch_bounds__(256) void cast_f16x8(
    const float* __restrict__ src, unsigned short* __restrict__ dst) {
  const size_t t = (size_t)blockIdx.x * 256 + threadIdx.x;
  const float4* s = (const float4*)src + t * 2;
  const float4 a = s[0], b = s[1];
  HU u;
  u.h[0] = (_Float16)a.x; u.h[1] = (_Float16)a.y;
  u.h[2] = (_Float16)a.z; u.h[3] = (_Float16)a.w;
  u.h[4] = (_Float16)b.x; u.h[5] = (_Float16)b.y;
  u.h[6] = (_Float16)b.z; u.h[7] = (_Float16)b.w;
  ((u16x8*)dst)[t] = u.v;
}

// ---------------------------------------------------------------------------
// prep_wb: Wb[n][k] = bf16(conv_w[n][k] * inv[n]); bias[n] = beta - mean*inv.
// ---------------------------------------------------------------------------
__global__ __launch_bounds__(256) void prep_wb(
    const float* __restrict__ cw, const float* __restrict__ gamma,
    const float* __restrict__ beta, const float* __restrict__ mean,
    const float* __restrict__ var, unsigned short* __restrict__ wb,
    float* __restrict__ bias) {
  const int n = blockIdx.x;
  const float inv = gamma[n] * rsqrtf(var[n] + 1e-5f);
  if (threadIdx.x == 0) bias[n] = beta[n] - mean[n] * inv;
  for (int k = threadIdx.x; k < KDIM; k += 256)
    wb[(size_t)n * KDIM + k] = f2bf(cw[(size_t)n * KDIM + k] * inv);
}

// ---------------------------------------------------------------------------
// prep_aim: im2col to bf16. Aim[m=(b,px)][k=ci*9+tap]
// ---------------------------------------------------------------------------
__global__ __launch_bounds__(256) void prep_aim(
    const float* __restrict__ x, unsigned short* __restrict__ aim) {
  __shared__ float lxp[32 * 100];
  const int b = blockIdx.x;
  const int ci0 = blockIdx.y * 32;
  const int tid = threadIdx.x;
  for (int t = tid; t < 3200; t += 256) lxp[t] = 0.f;
  __syncthreads();
  for (int t = tid; t < 2048; t += 256) {
    const int ci = t >> 6, px = t & 63;
    lxp[ci * 100 + 11 + (px >> 3) * 10 + (px & 7)] =
        x[((size_t)b * PCH + ci0 + ci) * 64 + px];
  }
  __syncthreads();
  for (int t = tid; t < 4608; t += 256) {
    const int px = t / 72;
    const int kk = (t - px * 72) * 4;
    unsigned short v[4];
#pragma unroll
    for (int j = 0; j < 4; ++j) {
      const int k = kk + j;
      const int ci = k / 9;
      const int tap = k - ci * 9;
      const int kh = tap / 3, kw = tap - kh * 3;
      v[j] = f2bf(lxp[ci * 100 + ((px >> 3) + kh) * 10 + (px & 7) + kw]);
    }
    ushort4* dst =
        (ushort4*)(aim + (size_t)(b * 64 + px) * KDIM + ci0 * 9 + kk);
    *dst = make_ushort4(v[0], v[1], v[2], v[3]);
  }
}

// ---------------------------------------------------------------------------
// conv_gemm: 64x64 tiles, mfma 16x16x32_bf16, global_load_lds staging with
// XOR swizzle, fused bias+ReLU+squash -> pose_h (f16).
// ---------------------------------------------------------------------------
__global__ __launch_bounds__(256) void conv_gemm(
    const unsigned short* __restrict__ aim, const unsigned short* __restrict__ wb,
    const float* __restrict__ bias, unsigned short* __restrict__ pose_h) {
  __shared__ unsigned short lA[64 * 64];
  __shared__ unsigned short lB[64 * 64];
  const int tid = threadIdx.x;
  const int lane = tid & 63, wv = tid >> 6;
  const int wm = wv & 1, wn = wv >> 1;
  const int m0 = blockIdx.x * 64;  // = batch * 64
  const int n0 = blockIdx.y * 64;
  const int rsub = lane >> 3, seg = lane & 7;

  f32x4 acc[2][2];
#pragma unroll
  for (int a = 0; a < 2; ++a)
#pragma unroll
    for (int c = 0; c < 2; ++c) acc[a][c] = (f32x4){0.f, 0.f, 0.f, 0.f};

  for (int k0 = 0; k0 < KDIM; k0 += 64) {
    __syncthreads();
#pragma unroll
    for (int it = 0; it < 2; ++it) {
      const int r = it * 32 + wv * 8 + rsub;
      const int c = seg ^ (r & 7);
      const unsigned short* ga = aim + (size_t)(m0 + r) * KDIM + k0 + c * 8;
      __builtin_amdgcn_global_load_lds(
          (const __attribute__((address_space(1))) void*)ga,
          (__attribute__((address_space(3))) void*)(lA + (it * 32 + wv * 8) * 64),
          16, 0, 0);
      const unsigned short* gb = wb + (size_t)(n0 + r) * KDIM + k0 + c * 8;
      __builtin_amdgcn_global_load_lds(
          (const __attribute__((address_space(1))) void*)gb,
          (__attribute__((address_space(3))) void*)(lB + (it * 32 + wv * 8) * 64),
          16, 0, 0);
    }
    __syncthreads();
#pragma unroll
    for (int kc = 0; kc < 2; ++kc) {
      const int g = kc * 4 + (lane >> 4);
      const int ml = wm * 32 + (lane & 15);
      const int nl = wn * 32 + (lane & 15);
      const int sa = (g ^ (ml & 7)) * 8;
      const int sb = (g ^ (nl & 7)) * 8;
      const bf16x8 a0 = *(const bf16x8*)(lA + (ml + 0) * 64 + sa);
      const bf16x8 a1 = *(const bf16x8*)(lA + (ml + 16) * 64 + sa);
      const bf16x8 b0 = *(const bf16x8*)(lB + (nl + 0) * 64 + sb);
      const bf16x8 b1 = *(const bf16x8*)(lB + (nl + 16) * 64 + sb);
      acc[0][0] = __builtin_amdgcn_mfma_f32_16x16x32_bf16(a0, b0, acc[0][0], 0, 0, 0);
      acc[0][1] = __builtin_amdgcn_mfma_f32_16x16x32_bf16(a0, b1, acc[0][1], 0, 0, 0);
      acc[1][0] = __builtin_amdgcn_mfma_f32_16x16x32_bf16(a1, b0, acc[1][0], 0, 0, 0);
      acc[1][1] = __builtin_amdgcn_mfma_f32_16x16x32_bf16(a1, b1, acc[1][1], 0, 0, 0);
    }
  }

  const int bq = blockIdx.x;
  float bsv[2];
#pragma unroll
  for (int ni = 0; ni < 2; ++ni)
    bsv[ni] = bias[n0 + wn * 32 + ni * 16 + (lane & 15)];
#pragma unroll
  for (int mi = 0; mi < 2; ++mi) {
#pragma unroll
    for (int ni = 0; ni < 2; ++ni) {
      const int n = n0 + wn * 32 + ni * 16 + (lane & 15);
#pragma unroll
      for (int reg = 0; reg < 4; ++reg) {
        float v = fmaxf(acc[mi][ni][reg] + bsv[ni], 0.f);
        float s2 = v * v;
        s2 += __shfl_xor(s2, 1, 64);
        s2 += __shfl_xor(s2, 2, 64);
        s2 += __shfl_xor(s2, 4, 64);
        const float sc = s2 / (1.f + s2) / (sqrtf(s2) + 1e-8f);
        const int px = wm * 32 + mi * 16 + (lane >> 4) * 4 + reg;
        pose_h[((size_t)bq * I_CAPS + (n >> 3) * 64 + px) * IDC + (n & 7)] =
            f2h(v * sc);
      }
    }
  }
}

// ---------------------------------------------------------------------------
// caps_v0 v2: phase-0 routing as f16 MFMA GEMM (c uniform; 1/32 in reduce).
// 128-way k-split, grid (8, KSPLIT) = 1024 blocks.
// ---------------------------------------------------------------------------
__global__ __launch_bounds__(256) void caps_v0(
    const unsigned short* __restrict__ pose_h,
    const unsigned short* __restrict__ wrh, float* __restrict__ pv0) {
  __shared__ unsigned short lA[64 * 64];
  __shared__ unsigned short lB[64 * 64];
  const int tid = threadIdx.x;
  const int lane = tid & 63, wv = tid >> 6;
  const int wm = wv & 1, wn = wv >> 1;
  const int o0 = blockIdx.x * 4;
  const int ks = blockIdx.y;
  const int rsub = lane >> 3, seg = lane & 7;

  f32x4 acc[2][2];
#pragma unroll
  for (int a = 0; a < 2; ++a)
#pragma unroll
    for (int c = 0; c < 2; ++c) acc[a][c] = (f32x4){0.f, 0.f, 0.f, 0.f};

  for (int kt = 0; kt < 4; ++kt) {
    const int k0 = ks * 256 + kt * 64;
    const int i0 = k0 >> 3;
    __syncthreads();
#pragma unroll
    for (int it = 0; it < 2; ++it) {
      const int r = it * 32 + wv * 8 + rsub;
      const int c = seg ^ (r & 7);
      const unsigned short* ga = pose_h + (size_t)r * 32768 + k0 + c * 8;
      __builtin_amdgcn_global_load_lds(
          (const __attribute__((address_space(1))) void*)ga,
          (__attribute__((address_space(3))) void*)(lA + (it * 32 + wv * 8) * 64),
          16, 0, 0);
    }
#pragma unroll
    for (int h = 0; h < 2; ++h) {
      const int idx = h * 256 + tid;
      const int d = idx & 15;
      const int il = (idx >> 4) & 7;
      const int ol = idx >> 7;
      const u16x8 v = *(const u16x8*)(wrh + (size_t)(o0 + ol) * 524288 +
                                      (size_t)(i0 + il) * 128 + d * 8);
      const int np = ol * 16 + d;
      *(u16x8*)(lB + np * 64 + (il ^ (np & 7)) * 8) = v;
    }
    __syncthreads();
#pragma unroll
    for (int kc = 0; kc < 2; ++kc) {
      const int g = kc * 4 + (lane >> 4);
      const int ml = wm * 32 + (lane & 15);
      const int nl = wn * 32 + (lane & 15);
      const int sa = (g ^ (ml & 7)) * 8;
      const int sb = (g ^ (nl & 7)) * 8;
      const f16x8v a0 = *(const f16x8v*)(lA + (ml + 0) * 64 + sa);
      const f16x8v a1 = *(const f16x8v*)(lA + (ml + 16) * 64 + sa);
      const f16x8v b0 = *(const f16x8v*)(lB + (nl + 0) * 64 + sb);
      const f16x8v b1 = *(const f16x8v*)(lB + (nl + 16) * 64 + sb);
      acc[0][0] = __builtin_amdgcn_mfma_f32_16x16x32_f16(a0, b0, acc[0][0], 0, 0, 0);
      acc[0][1] = __builtin_amdgcn_mfma_f32_16x16x32_f16(a0, b1, acc[0][1], 0, 0, 0);
      acc[1][0] = __builtin_amdgcn_mfma_f32_16x16x32_f16(a1, b0, acc[1][0], 0, 0, 0);
      acc[1][1] = __builtin_amdgcn_mfma_f32_16x16x32_f16(a1, b1, acc[1][1], 0, 0, 0);
    }
  }
#pragma unroll
  for (int mi = 0; mi < 2; ++mi) {
#pragma unroll
    for (int ni = 0; ni < 2; ++ni) {
      const int n = blockIdx.x * 64 + wn * 32 + ni * 16 + (lane & 15);
#pragma unroll
      for (int reg = 0; reg < 4; ++reg) {
        const int m = wm * 32 + mi * 16 + (lane >> 4) * 4 + reg;
        pv0[(size_t)(ks * 64 + m) * 512 + n] = acc[mi][ni][reg];
      }
    }
  }
}

// ---------------------------------------------------------------------------
// reduce_v0: sum KSPLIT k-splits, scale 1/32, squash over d -> vbuf (= v0).
// ---------------------------------------------------------------------------
__global__ __launch_bounds__(256) void reduce_v0(
    const float* __restrict__ pv0, float* __restrict__ vbuf) {
  const int t = blockIdx.x * 256 + threadIdx.x;
  const int b = t >> 9;
  const int r = t & 511;
  float s = 0.f;
#pragma unroll 8
  for (int ks = 0; ks < KSPLIT; ++ks)
    s += pv0[(size_t)(ks * 64 + b) * 512 + r];
  s *= (1.0f / 32.0f);
  float sq = s * s;
  sq += __shfl_xor(sq, 1, 64);
  sq += __shfl_xor(sq, 2, 64);
  sq += __shfl_xor(sq, 4, 64);
  sq += __shfl_xor(sq, 8, 64);
  const float sc = sq / (1.f + sq) / (sqrtf(sq) + 1e-8f);
  vbuf[t] = s * sc;
}

// ---------------------------------------------------------------------------
// Routing phase v11: v10 -> (a) ppose layout [b][i] (v10's [i][b] write was a
// 16-way bank conflict: stride 256B across 16 lanes -> 229K conflicts), and
// (b) process i in PAIRS with pair-wise double-buffered W staging:
// lw[2 pairbuf][2 i][8*65]. One barrier per pair (8 vs 16) and FOUR
// independent softmax shuffle chains (2 h x 2 bb) per barrier window for the
// in-order wave scheduler to interleave (was 2). LDS 37.3 KB -> 4 blocks/CU.
// ---------------------------------------------------------------------------
__global__ __launch_bounds__(512, 4) void routing_phase(
    const unsigned short* __restrict__ pose_h,
    const unsigned short* __restrict__ wrh,
    const float* __restrict__ vb, float* __restrict__ partials) {
  __shared__ u16x8 lw[2][2][8 * 65];  // [pairbuf][i-in-pair][row] 33.3 KB
  __shared__ u16x8 ppose[16][16];     // [b][i] 4 KB
  const int tid = threadIdx.x;
  const int lane = tid & 63;
  const int wv = tid >> 6;  // 0..7
  const int o = lane >> 1, dh = lane & 1;
  const int i0 = blockIdx.x * ICHUNK;
  const int b0 = blockIdx.y * 16;

  const int sl = tid >> 3;  // 0..63
  const int sq = tid & 7;
  const u16x8* wr8 = (const u16x8*)wrh;

  float acc[2][8];
  float vr[2][8];
#pragma unroll
  for (int bb = 0; bb < 2; ++bb) {
    const int b = b0 + wv * 2 + bb;
    const float4* vp =
        (const float4*)(vb + ((size_t)(b * O_CAPS + o) * OD) + dh * 8);
    const float4 v0 = vp[0], v1 = vp[1];
    vr[bb][0] = v0.x; vr[bb][1] = v0.y; vr[bb][2] = v0.z; vr[bb][3] = v0.w;
    vr[bb][4] = v1.x; vr[bb][5] = v1.y; vr[bb][6] = v1.z; vr[bb][7] = v1.w;
#pragma unroll
    for (int j = 0; j < 8; ++j) acc[bb][j] = 0.f;
  }

  auto stage = [&](int i, int pb, int h) {
    lw[pb][h][sq * 65 + sl] =
        wr8[(size_t)(sl >> 1) * (I_CAPS * 16) + (size_t)i * 16 +
            (sl & 1) * 8 + sq];
  };

  if (tid < 256) {  // pose tile [b][i]: write stride 16B (conflict-free)
    const int pb = tid >> 4, pi = tid & 15;
    ppose[pb][pi] =
        *(const u16x8*)(pose_h + ((size_t)(b0 + pb) * I_CAPS + i0 + pi) * IDC);
  }
  stage(i0, 0, 0);
  stage(i0 + 1, 0, 1);
  __syncthreads();

  for (int ip = 0; ip < ICHUNK / 2; ++ip) {
    const int buf = ip & 1;
    if (ip + 1 < ICHUNK / 2) {
      stage(i0 + 2 * ip + 2, buf ^ 1, 0);
      stage(i0 + 2 * ip + 3, buf ^ 1, 1);
    }
#pragma unroll
    for (int h = 0; h < 2; ++h) {
      const int ii = 2 * ip + h;
      HU w[8];
#pragma unroll
      for (int q = 0; q < 8; ++q) w[q].v = lw[buf][h][q * 65 + lane];
#pragma unroll
      for (int bb = 0; bb < 2; ++bb) {
        HU pk;
        pk.v = ppose[wv * 2 + bb][ii];  // wave-uniform broadcast
        float X[8];
#pragma unroll
        for (int j = 0; j < 8; ++j) {
#ifdef HAVE_FDOT2
          float s = __builtin_amdgcn_fdot2(w[j].p[3], pk.p[3], 0.f, false);
          s = __builtin_amdgcn_fdot2(w[j].p[2], pk.p[2], s, false);
          s = __builtin_amdgcn_fdot2(w[j].p[1], pk.p[1], s, false);
          X[j] = __builtin_amdgcn_fdot2(w[j].p[0], pk.p[0], s, false);
#else
          float s = 0.f;
#pragma unroll
          for (int k = 0; k < 8; ++k) s += (float)w[j].h[k] * (float)pk.h[k];
          X[j] = s;
#endif
        }
        float lg = 0.f;
#pragma unroll
        for (int j = 0; j < 8; ++j) lg += vr[bb][j] * X[j];
        lg += __shfl_xor(lg, 1, 64);  // full v.X over 16 d
        const float e = __expf(lg);   // no max-subtract: |lg| small
        float sm = e;
#pragma unroll
        for (int s = 2; s < 64; s <<= 1) sm += __shfl_xor(sm, s, 64);
        const float c = e / sm;
#pragma unroll
        for (int j = 0; j < 8; ++j) acc[bb][j] += c * X[j];
      }
    }
    __syncthreads();
  }

  const size_t pbase = ((size_t)blockIdx.x * 4 + blockIdx.y) * (16 * 512);
#pragma unroll
  for (int bb = 0; bb < 2; ++bb) {
    const int bl = wv * 2 + bb;
    float4* dst =
        (float4*)(partials + pbase + (size_t)bl * 512 + o * 16 + dh * 8);
    dst[0] = make_float4(acc[bb][0], acc[bb][1], acc[bb][2], acc[bb][3]);
    dst[1] = make_float4(acc[bb][4], acc[bb][5], acc[bb][6], acc[bb][7]);
  }
}

// ---------------------------------------------------------------------------
// reduce_squash<ADDV>: sum 256 i-chunk partials, squash over d; if ADDV,
// add vprev (producing vsum = v0 + v1 for the final routing pass).
// Partials layout: [(iblk*4 + bgrp)][16 b][512] (R3-proven).
// ---------------------------------------------------------------------------
template <int ADDV>
__global__ __launch_bounds__(256) void reduce_squash(
    const float* __restrict__ partials, const float* __restrict__ vprev,
    float* __restrict__ dst) {
  const int t = blockIdx.x * 256 + threadIdx.x;  // (b, od)
  const int b = t >> 9;
  const int r = t & 511;
  const int bg = b >> 4, bl = b & 15;
  const size_t elem = (size_t)bl * 512 + r;
  float s = 0.f;
  for (int blk = 0; blk < NPBLK; ++blk)
    s += partials[(size_t)(blk * 4 + bg) * (16 * 512) + elem];
  float sq = s * s;
  sq += __shfl_xor(sq, 1, 64);
  sq += __shfl_xor(sq, 2, 64);
  sq += __shfl_xor(sq, 4, 64);
  sq += __shfl_xor(sq, 8, 64);
  const float sc = sq / (1.f + sq) / (sqrtf(sq) + 1e-8f);
  float val = s * sc;
  if (ADDV) val += vprev[t];
  dst[t] = val;
}

// ---------------------------------------------------------------------------
// vae_head: fused fc1(relu)+fc2(z_mu)+fc_var over 2048 rows; 512 blk x 1024.
// ---------------------------------------------------------------------------
__global__ __launch_bounds__(1024) void vae_head(
    const float* __restrict__ outc, const float* __restrict__ w1,
    const float* __restrict__ b1, const float* __restrict__ w2,
    const float* __restrict__ b2, const float* __restrict__ wv,
    const float* __restrict__ bv, float* __restrict__ dout) {
  __shared__ float lo[4][16];
  __shared__ float lh[4][1024];
  __shared__ float red[16][4][64];
  const int n0 = blockIdx.x * 4;
  const int tid = threadIdx.x;
  if (tid < 64) lo[tid >> 4][tid & 15] = outc[(size_t)n0 * 16 + tid];
  __syncthreads();

  {
    const float bb = b1[tid];
    float h0 = bb, h1 = bb, h2v = bb, h3 = bb;
#pragma unroll
    for (int k = 0; k < 16; ++k) {
      const float w = w1[(size_t)k * 1024 + tid];
      h0 += lo[0][k] * w;
      h1 += lo[1][k] * w;
      h2v += lo[2][k] * w;
      h3 += lo[3][k] * w;
    }
    lh[0][tid] = fmaxf(h0, 0.f);
    lh[1][tid] = fmaxf(h1, 0.f);
    lh[2][tid] = fmaxf(h2v, 0.f);
    lh[3][tid] = fmaxf(h3, 0.f);
  }
  __syncthreads();

  const int m = tid & 63, sl = tid >> 6;
  {
    float a0 = 0.f, a1 = 0.f, a2 = 0.f, a3 = 0.f;
    const int j0 = sl * 64;
#pragma unroll 4
    for (int jj = 0; jj < 64; ++jj) {
      const int j = j0 + jj;
      const float w = w2[(size_t)j * 64 + m];
      a0 += lh[0][j] * w;
      a1 += lh[1][j] * w;
      a2 += lh[2][j] * w;
      a3 += lh[3][j] * w;
    }
    red[sl][0][m] = a0;
    red[sl][1][m] = a1;
    red[sl][2][m] = a2;
    red[sl][3][m] = a3;
  }
  __syncthreads();

  if (tid < 256) {
    const int r = tid >> 6;
    float z = b2[m];
#pragma unroll
    for (int s = 0; s < 16; ++s) z += red[s][r][m];
    const int n = n0 + r;
    dout[n * 64 + m] = z;
    dout[131072 + n * 64 + m] = z;
    float sv = bv[m];
#pragma unroll
    for (int k = 0; k < 16; ++k) sv += lo[r][k] * wv[(size_t)k * 64 + m];
    const float sp =
        (sv > 0.f) ? (sv + log1pf(__expf(-sv))) : log1pf(__expf(sv));
    dout[262144 + n * 64 + m] = sp + 1e-8f;
  }
}

// ---------------------------------------------------------------------------
extern "C" void kernel_launch(void* const* d_in, const int* in_sizes, int n_in,
                              void* d_out, int out_size, void* d_ws,
                              size_t ws_size, hipStream_t stream) {
  const float* x = (const float*)d_in[0];
  const float* conv_w = (const float*)d_in[1];
  const float* bn_gamma = (const float*)d_in[2];
  const float* bn_beta = (const float*)d_in[3];
  const float* bn_mean = (const float*)d_in[4];
  const float* bn_var = (const float*)d_in[5];
  const float* caps_w = (const float*)d_in[6];
  const float* fcm_w1 = (const float*)d_in[7];
  const float* fcm_b1 = (const float*)d_in[8];
  const float* fcm_w2 = (const float*)d_in[9];
  const float* fcm_b2 = (const float*)d_in[10];
  const float* fcv_w = (const float*)d_in[11];
  const float* fcv_b = (const float*)d_in[12];
  float* out = (float*)d_out;
  float* ws = (float*)d_ws;

  unsigned short* pose_h = (unsigned short*)(ws + OFF_PH);
  float* part = ws + OFF_PART;
  float* pv0 = ws + OFF_PV0;
  float* vbuf = ws + OFF_VBUF;
  float* vbuf2 = ws + OFF_VBUF2;
  float* outc = ws + OFF_OUTC;
  unsigned short* wbq = (unsigned short*)(ws + OFF_WB);
  float* bias = ws + OFF_BIAS;
  unsigned short* wrh = (unsigned short*)(ws + OFF_WRH);
  unsigned short* aim = (unsigned short*)(ws + OFF_AIM);

  cast_f16x8<<<8192, 256, 0, stream>>>(caps_w, wrh);
  prep_wb<<<512, 256, 0, stream>>>(conv_w, bn_gamma, bn_beta, bn_mean, bn_var,
                                   wbq, bias);
  prep_aim<<<dim3(64, 16), 256, 0, stream>>>(x, aim);
  conv_gemm<<<dim3(64, 8), 256, 0, stream>>>(aim, wbq, bias, pose_h);

  // iter 0: uniform c as f16 MFMA GEMM -> v0 (128-way k-split)
  caps_v0<<<dim3(8, KSPLIT), 256, 0, stream>>>(pose_h, wrh, pv0);
  reduce_v0<<<128, 256, 0, stream>>>(pv0, vbuf);

  // iter 1: logits = v0.X
  routing_phase<<<dim3(NPBLK, 4), 512, 0, stream>>>(pose_h, wrh, vbuf, part);
  reduce_squash<1><<<128, 256, 0, stream>>>(part, vbuf, vbuf2);  // vsum = v0+v1

  // iter 2: logits = (v0+v1).X
  routing_phase<<<dim3(NPBLK, 4), 512, 0, stream>>>(pose_h, wrh, vbuf2, part);
  reduce_squash<0><<<128, 256, 0, stream>>>(part, nullptr, outc);

  vae_head<<<512, 1024, 0, stream>>>(outc, fcm_w1, fcm_b1, fcm_w2, fcm_b2,
                                     fcv_w, fcv_b, out);
}